// Round 1
// baseline (240.221 us; speedup 1.0000x reference)
//
#include <hip/hip_runtime.h>
#include <hip/hip_bf16.h>
#include <math.h>

typedef __bf16 bf16;
typedef __attribute__((ext_vector_type(8))) __bf16 bf16x8;
typedef __attribute__((ext_vector_type(2))) float f32x2;
typedef __attribute__((ext_vector_type(4))) float f32x4;
typedef __attribute__((ext_vector_type(4))) unsigned int uint4v;

#define MFMA16(a, b, c) __builtin_amdgcn_mfma_f32_16x16x32_bf16(a, b, c, 0, 0, 0)

// 1/sqrt(96) * log2(e): folded into Qb so attn scores are already in log2 domain.
#define QSCALE 0.14724450f

__device__ __forceinline__ void async16(void* lds, const void* g) {
    __builtin_amdgcn_global_load_lds(
        (const __attribute__((address_space(1))) unsigned int*)g,
        (__attribute__((address_space(3))) unsigned int*)lds, 16, 0, 0);
}

__device__ __forceinline__ bf16x8 cvt8v(f32x4 lo, f32x4 hi) {
    bf16x8 r;
    r[0] = (bf16)lo[0]; r[1] = (bf16)lo[1]; r[2] = (bf16)lo[2]; r[3] = (bf16)lo[3];
    r[4] = (bf16)hi[0]; r[5] = (bf16)hi[1]; r[6] = (bf16)hi[2]; r[7] = (bf16)hi[3];
    return r;
}

// ---------------- Kernel 0: convert all 8 weight matrices fp32 -> bf16 ----------------
// Wb slots: 0 t_cls, 1 d_cls, 2 v_cls, 3 tgl_q, 4 tgl_k, 5 tgl_v, 6 t_tok, 7 v_patch

struct WPtrs { const float* W[8]; };

__global__ __launch_bounds__(256) void cvtw_kernel(WPtrs wp, bf16* __restrict__ Wb) {
    int j   = blockIdx.x / 48;
    int blk = blockIdx.x - j * 48;
    int idx = (blk * 256 + threadIdx.x) * 4;
    f32x4 v = *(const f32x4*)(wp.W[j] + idx);
    bf16* dst = Wb + j * 49152 + idx;
    dst[0] = (bf16)v[0]; dst[1] = (bf16)v[1]; dst[2] = (bf16)v[2]; dst[3] = (bf16)v[3];
}

// ---------------- Kernel 1: all 8 projections, async-LDS staged ----------------
// Block = 32 rows x K=512. X tile staged fp32 -> LDS via global_load_lds in 4
// double-buffered 128-col chunks (16 KB each), XOR-swizzled (slot ^= row&15,
// swizzle applied on the GLOBAL source so LDS writes stay lane-linear).
// 4 waves = (nh col-half 48, rh row-half 16): full-K accumulate per wave, no
// K-split reduction. KVT blocks (NSUB=3) compute K/V/t_tok from one staged
// Z_t_tok tile (3x MFMA per staged byte).

struct ProjParams {
    const float* src[8];
    const float* B[8];
    void* dst[8];
    const bf16* Wb;
};

__device__ __forceinline__ void stageX(const float* X, int r0, int c, char* dstb,
                                       int w4, int lane) {
    #pragma unroll
    for (int it = 0; it < 4; it++) {
        int bidx = it * 256 + w4 * 64;     // wave-uniform LDS base (HW adds lane*16)
        int idx  = bidx + lane;
        int row  = idx >> 5, sp = idx & 31;
        int sl   = sp ^ (row & 15);        // pre-swizzled global source
        async16(dstb + (size_t)bidx * 16,
                X + (size_t)(r0 + row) * 512 + c * 128 + sl * 4);
    }
}

template<int NSUB, bool F32OUT>
__device__ __forceinline__ void proj_body(
    const float* __restrict__ X, int r0, const bf16* __restrict__ Wj,
    const float* B0, const float* B1, const float* B2,
    void* D0, void* D1, void* D2,
    int normMask, float scale,
    char* Xp, float (*sx)[2][32], int tid)
{
    int w4 = tid >> 6, lane = tid & 63;
    int nh = w4 & 1, rh = w4 >> 1;
    int m = lane & 15, quad = lane >> 4;

    const bf16* wbL = Wj + (size_t)(nh * 48 + m) * 512 + quad * 8;

    f32x4 acc[3 * NSUB] = {};

    stageX(X, r0, 0, Xp, w4, lane);
    __syncthreads();
    #pragma unroll
    for (int c = 0; c < 4; c++) {
        int bb = c & 1;
        if (c < 3) stageX(X, r0, c + 1, Xp + (bb ^ 1) * 16384, w4, lane);
        const char* xb = Xp + bb * 16384 + (rh * 16 + m) * 512;
        #pragma unroll
        for (int kkk = 0; kkk < 4; kkk++) {
            int sl = kkk * 8 + quad * 2;
            f32x4 lo = *(const f32x4*)(xb + ((sl ^ m) * 16));
            f32x4 hi = *(const f32x4*)(xb + (((sl + 1) ^ m) * 16));
            bf16x8 a = cvt8v(lo, hi);
            const bf16* wk = wbL + c * 128 + kkk * 32;
            #pragma unroll
            for (int j = 0; j < NSUB; j++)
                #pragma unroll
                for (int nt = 0; nt < 3; nt++)
                    acc[j * 3 + nt] = MFMA16(a, *(const bf16x8*)(wk + j * 49152 + nt * 8192),
                                             acc[j * 3 + nt]);
        }
        __syncthreads();
    }

    // epilogue: bias (+scale), optional l2-norm with cross-nh exchange, store.
    float ss[NSUB][4];
    #pragma unroll
    for (int j = 0; j < NSUB; j++) {
        const float* Bj = (j == 0) ? B0 : ((j == 1) ? B1 : B2);
        #pragma unroll
        for (int nt = 0; nt < 3; nt++) {
            float bv = Bj[nh * 48 + nt * 16 + m];
            #pragma unroll
            for (int r = 0; r < 4; r++)
                acc[j * 3 + nt][r] = (acc[j * 3 + nt][r] + bv) * scale;
        }
        if ((normMask >> j) & 1) {
            #pragma unroll
            for (int r = 0; r < 4; r++) {
                float s = 0.0f;
                #pragma unroll
                for (int nt = 0; nt < 3; nt++) s += acc[j * 3 + nt][r] * acc[j * 3 + nt][r];
                s += __shfl_xor(s, 1); s += __shfl_xor(s, 2);
                s += __shfl_xor(s, 4); s += __shfl_xor(s, 8);
                ss[j][r] = s;
            }
            if (m == 0) {
                #pragma unroll
                for (int r = 0; r < 4; r++)
                    sx[j][nh][rh * 16 + quad * 4 + r] = ss[j][r];
            }
        }
    }
    __syncthreads();
    #pragma unroll
    for (int j = 0; j < NSUB; j++) {
        if ((normMask >> j) & 1) {
            #pragma unroll
            for (int r = 0; r < 4; r++) {
                float tot = ss[j][r] + sx[j][1 - nh][rh * 16 + quad * 4 + r];
                float inv = 1.0f / fmaxf(sqrtf(tot), 1e-6f);
                #pragma unroll
                for (int nt = 0; nt < 3; nt++) acc[j * 3 + nt][r] *= inv;
            }
        }
        void* Dj = (j == 0) ? D0 : ((j == 1) ? D1 : D2);
        #pragma unroll
        for (int nt = 0; nt < 3; nt++)
            #pragma unroll
            for (int r = 0; r < 4; r++) {
                size_t o = (size_t)(r0 + rh * 16 + quad * 4 + r) * 96 + nh * 48 + nt * 16 + m;
                if constexpr (F32OUT) ((float*)Dj)[o] = acc[j * 3 + nt][r];
                else                  ((bf16*)Dj)[o] = (bf16)acc[j * 3 + nt][r];
            }
    }
}

// Grid: [0,256) KVT (heaviest first), [256,512) Q, [512,904) v_patch, [904,910) cls.
__global__ __launch_bounds__(256) void proj_kernel(ProjParams p) {
    __shared__ __align__(16) char Xp[32768];
    __shared__ float sx[3][2][32];
    int g = blockIdx.x, tid = threadIdx.x;
    if (g < 256) {
        proj_body<3, false>(p.src[4], g << 5, p.Wb + 4 * 49152,
                            p.B[4], p.B[5], p.B[6], p.dst[4], p.dst[5], p.dst[6],
                            4, 1.0f, Xp, sx, tid);
    } else if (g < 512) {
        proj_body<1, false>(p.src[3], (g - 256) << 5, p.Wb + 3 * 49152,
                            p.B[3], 0, 0, p.dst[3], 0, 0,
                            0, QSCALE, Xp, sx, tid);
    } else if (g < 904) {
        proj_body<1, false>(p.src[7], (g - 512) << 5, p.Wb + 7 * 49152,
                            p.B[7], 0, 0, p.dst[7], 0, 0,
                            1, 1.0f, Xp, sx, tid);
    } else {
        int jb = (g - 904) >> 1;
        proj_body<1, true>(p.src[jb], ((g - 904) & 1) << 5, p.Wb + jb * 49152,
                           p.B[jb], 0, 0, p.dst[jb], 0, 0,
                           1, 1.0f, Xp, sx, tid);
    }
}

// ---------------- Kernel 2: TGL attention per (b,c) pair -> ctx[96] ----------------
// EXACT R9 form (4096 independent blocks — R12 proved pair-batching loses TLP).
// LDS K-staging; scores log2-scaled (QSCALE in Qb); softmax w/o max-subtraction.

__global__ __launch_bounds__(256) void attn_kernel(
    const bf16* __restrict__ Qg, const bf16* __restrict__ Kg, const bf16* __restrict__ Vg,
    float* __restrict__ Ctx)
{
    int pr = blockIdx.x;
    int b = pr >> 6, c = pr & 63;
    int tid = threadIdx.x, lane = tid & 63, w = tid >> 6;
    int m = lane & 15, quad = lane >> 4;
    const bf16* Q = Qg + (size_t)b * (128 * 96);
    const bf16* K = Kg + (size_t)c * (128 * 96);
    const bf16* V = Vg + (size_t)c * (128 * 96);

    __shared__ __align__(16) bf16 Klds[128 * 104];
    #pragma unroll
    for (int it = 0; it < 6; it++) {
        int ch = it * 256 + tid;
        int row = ch / 12, seg = ch - row * 12;
        *(uint4v*)(Klds + row * 104 + seg * 8) = *(const uint4v*)(K + ch * 8);
    }
    __syncthreads();

    f32x4 acc[2][8] = {};
    #pragma unroll
    for (int kk = 0; kk < 96; kk += 32) {
        bf16x8 a0 = *(const bf16x8*)(Q + (size_t)(w * 32 + m) * 96 + kk + quad * 8);
        bf16x8 a1 = *(const bf16x8*)(Q + (size_t)(w * 32 + 16 + m) * 96 + kk + quad * 8);
        #pragma unroll
        for (int nt = 0; nt < 8; nt++) {
            bf16x8 bb = *(const bf16x8*)(Klds + (nt * 16 + m) * 104 + kk + quad * 8);
            acc[0][nt] = MFMA16(a0, bb, acc[0][nt]);
            acc[1][nt] = MFMA16(a1, bb, acc[1][nt]);
        }
    }
    float wpart[8];
    #pragma unroll
    for (int nt = 0; nt < 8; nt++) wpart[nt] = 0.0f;
    #pragma unroll
    for (int mt = 0; mt < 2; mt++) {
        #pragma unroll
        for (int r = 0; r < 4; r++) {
            float tv[8]; float s = 0.0f;
            #pragma unroll
            for (int nt = 0; nt < 8; nt++) { tv[nt] = exp2f(acc[mt][nt][r]); s += tv[nt]; }
            s += __shfl_xor(s, 1); s += __shfl_xor(s, 2);
            s += __shfl_xor(s, 4); s += __shfl_xor(s, 8);
            float inv = 1.0f / s;
            #pragma unroll
            for (int nt = 0; nt < 8; nt++) wpart[nt] += tv[nt] * inv;
        }
    }
    #pragma unroll
    for (int nt = 0; nt < 8; nt++) {
        wpart[nt] += __shfl_xor(wpart[nt], 16);
        wpart[nt] += __shfl_xor(wpart[nt], 32);
    }
    __shared__ float wsum4[4][128];
    __shared__ float wk[128];
    __shared__ float ctxp[4][96];
    if (lane < 16) {
        #pragma unroll
        for (int nt = 0; nt < 8; nt++) wsum4[w][nt * 16 + lane] = wpart[nt];
    }
    __syncthreads();
    if (tid < 128) wk[tid] = wsum4[0][tid] + wsum4[1][tid] + wsum4[2][tid] + wsum4[3][tid];
    __syncthreads();
    {
        float c0 = 0.0f, c1 = 0.0f;
        if (lane < 48) {
            #pragma unroll 4
            for (int r = 0; r < 32; r++) {
                int k = w * 32 + r;
                unsigned u = *(const unsigned*)(V + (size_t)k * 96 + lane * 2);
                float lo = __uint_as_float(u << 16);
                float hi = __uint_as_float(u & 0xffff0000u);
                float wkk = wk[k];
                c0 += wkk * lo; c1 += wkk * hi;
            }
            ctxp[w][lane * 2]     = c0;
            ctxp[w][lane * 2 + 1] = c1;
        }
    }
    __syncthreads();
    if (tid < 96)
        Ctx[(size_t)pr * 96 + tid] =
            (ctxp[0][tid] + ctxp[1][tid] + ctxp[2][tid] + ctxp[3][tid]) * (1.0f / 128.0f);
}

// ---------------- Kernel 3: CLL + fused epilogue ----------------
// Block = (c, bgroup): stage v_pat_c once, loop 8 b-tiles of t_tok (max-sim),
// then each wave runs the LN/l2n/dots epilogue for 2 of the block's 8 pairs and
// writes d_out directly (replaces epi_kernel; one less dispatch + gap).
// S_TGL uses d_i (row); tg uses d_j. DEFAULT launch_bounds (R6 spill lesson).

__global__ __launch_bounds__(256) void cll_kernel(
    const bf16* __restrict__ Tt, const bf16* __restrict__ Vp,
    const float* __restrict__ Ctx, const float* __restrict__ t,
    const float* __restrict__ d, const float* __restrict__ v,
    const float* __restrict__ ln_g, const float* __restrict__ ln_b,
    float* __restrict__ out)
{
    int c = blockIdx.x >> 3, bg = blockIdx.x & 7;
    int tid = threadIdx.x, lane = tid & 63, w = tid >> 6;
    int m = lane & 15, quad = lane >> 4;
    const bf16* P = Vp + (size_t)c * (196 * 96);

    __shared__ __align__(16) bf16 Plds[196 * 104];
    __shared__ float red[8][4];
    for (int ch = tid; ch < 2352; ch += 256) {
        int row = ch / 12, seg = ch - row * 12;
        *(uint4v*)(Plds + row * 104 + seg * 8) = *(const uint4v*)(P + ch * 8);
    }
    int rofs[13];
    #pragma unroll
    for (int nt = 0; nt < 13; nt++) {
        int r = nt * 16 + m; if (r > 195) r = 195;
        rofs[nt] = r * 104;
    }
    __syncthreads();

    for (int bi = 0; bi < 8; bi++) {
        const bf16* T = Tt + (size_t)(bg * 8 + bi) * (128 * 96);
        f32x4 acc[2][13] = {};
        #pragma unroll
        for (int kk = 0; kk < 96; kk += 32) {
            bf16x8 a0 = *(const bf16x8*)(T + (size_t)(w * 32 + m) * 96 + kk + quad * 8);
            bf16x8 a1 = *(const bf16x8*)(T + (size_t)(w * 32 + 16 + m) * 96 + kk + quad * 8);
            #pragma unroll
            for (int nt = 0; nt < 13; nt++) {
                bf16x8 bb = *(const bf16x8*)(Plds + rofs[nt] + kk + quad * 8);
                acc[0][nt] = MFMA16(a0, bb, acc[0][nt]);
                acc[1][nt] = MFMA16(a1, bb, acc[1][nt]);
            }
        }
        float mx = -3.4e38f;
        #pragma unroll
        for (int mt = 0; mt < 2; mt++)
            #pragma unroll
            for (int nt = 0; nt < 13; nt++)
                #pragma unroll
                for (int r = 0; r < 4; r++) mx = fmaxf(mx, acc[mt][nt][r]);
        #pragma unroll
        for (int dd = 1; dd < 64; dd <<= 1) mx = fmaxf(mx, __shfl_xor(mx, dd));
        if (lane == 0) red[bi][w] = mx;
    }
    __syncthreads();

    // fused epilogue: wave w handles bi = w and bi = w+4
    #pragma unroll
    for (int half = 0; half < 2; half++) {
        int bi = w + half * 4;
        int i  = bg * 8 + bi;          // b row
        int pr = i * 64 + c;
        float scll = fmaxf(fmaxf(red[bi][0], red[bi][1]), fmaxf(red[bi][2], red[bi][3]));
        bool act = lane < 48;
        float c0 = 0, c1 = 0, t0 = 0, t1 = 0;
        float dj0 = 0, dj1 = 0, di0 = 0, di1 = 0, v0 = 0, v1 = 0, g0 = 0, g1 = 0, bb0 = 0, bb1 = 0;
        if (act) {
            f32x2 cc  = *(const f32x2*)(Ctx + (size_t)pr * 96 + lane * 2);
            f32x2 tt  = *(const f32x2*)(t + i * 96 + lane * 2);
            f32x2 ddj = *(const f32x2*)(d + c * 96 + lane * 2);
            f32x2 ddi = *(const f32x2*)(d + i * 96 + lane * 2);
            f32x2 vv  = *(const f32x2*)(v + c * 96 + lane * 2);
            f32x2 gg  = *(const f32x2*)(ln_g + lane * 2);
            f32x2 bbv = *(const f32x2*)(ln_b + lane * 2);
            c0 = cc[0]; c1 = cc[1]; t0 = tt[0]; t1 = tt[1];
            dj0 = ddj[0]; dj1 = ddj[1]; di0 = ddi[0]; di1 = ddi[1];
            v0 = vv[0]; v1 = vv[1];
            g0 = gg[0]; g1 = gg[1]; bb0 = bbv[0]; bb1 = bbv[1];
        }
        float s = c0 + c1;
        #pragma unroll
        for (int k = 1; k < 64; k <<= 1) s += __shfl_xor(s, k);
        float mean = s * (1.0f / 96.0f);
        float e0 = act ? (c0 - mean) : 0.0f;
        float e1 = act ? (c1 - mean) : 0.0f;
        float q = e0 * e0 + e1 * e1;
        #pragma unroll
        for (int k = 1; k < 64; k <<= 1) q += __shfl_xor(q, k);
        float rstd = rsqrtf(q * (1.0f / 96.0f) + 1e-5f);
        float y0 = act ? (e0 * rstd * g0 + bb0) : 0.0f;
        float y1 = act ? (e1 * rstd * g1 + bb1) : 0.0f;
        float dot = y0 * di0 + y1 * di1;   // S_TGL uses d_i
        float ssq = y0 * y0 + y1 * y1;
        float tg  = t0 * dj0 + t1 * dj1;   // S_TGG uses d_j
        float cg  = t0 * v0 + t1 * v1;
        #pragma unroll
        for (int k = 1; k < 64; k <<= 1) {
            dot += __shfl_xor(dot, k); ssq += __shfl_xor(ssq, k);
            tg  += __shfl_xor(tg, k);  cg  += __shfl_xor(cg, k);
        }
        if (lane == 0) {
            float stgl = dot / fmaxf(sqrtf(ssq), 1e-6f);
            out[pr] = 0.5f * (tg + stgl) + 0.5f * (cg + scll);
        }
    }
}

// ---------------- launch ----------------

extern "C" void kernel_launch(void* const* d_in, const int* in_sizes, int n_in,
                              void* d_out, int out_size, void* d_ws, size_t ws_size,
                              hipStream_t stream)
{
    (void)in_sizes; (void)n_in; (void)out_size; (void)ws_size;
    char* ws = (char*)d_ws;
    float* t     = (float*)(ws + 0);               // 64*96 f32
    float* d     = (float*)(ws + 24576);
    float* v     = (float*)(ws + 49152);
    bf16* Wb = (bf16*)(ws + 106496);               // 8*96*512 bf16
    bf16* Qb = (bf16*)(ws + 892928);               // 8192*96 bf16
    bf16* Kb = (bf16*)(ws + 892928 + 1572864);
    bf16* Vb = (bf16*)(ws + 892928 + 2 * 1572864);
    bf16* Tt = (bf16*)(ws + 892928 + 3 * 1572864);
    bf16* Vp = (bf16*)(ws + 892928 + 4 * 1572864);         // 12544*96 bf16 = 2408448 B
    float* Ctx = (float*)(ws + 892928 + 4 * 1572864 + 2408448); // 4096*96 f32

    WPtrs wp;
    wp.W[0] = (const float*)d_in[6];   // W_t_cls
    wp.W[1] = (const float*)d_in[8];   // W_d_cls
    wp.W[2] = (const float*)d_in[10];  // W_v_cls
    wp.W[3] = (const float*)d_in[16];  // W_tgl_q
    wp.W[4] = (const float*)d_in[18];  // W_tgl_k
    wp.W[5] = (const float*)d_in[20];  // W_tgl_v
    wp.W[6] = (const float*)d_in[12];  // W_t_tok
    wp.W[7] = (const float*)d_in[14];  // W_v_patch
    hipLaunchKernelGGL(cvtw_kernel, dim3(384), dim3(256), 0, stream, wp, Wb);

    ProjParams pp;
    pp.Wb = Wb;
    pp.src[0] = (const float*)d_in[2];  pp.B[0] = (const float*)d_in[7];  pp.dst[0] = t;   // t_cls
    pp.src[1] = (const float*)d_in[0];  pp.B[1] = (const float*)d_in[9];  pp.dst[1] = d;   // d_cls
    pp.src[2] = (const float*)d_in[4];  pp.B[2] = (const float*)d_in[11]; pp.dst[2] = v;   // v_cls
    pp.src[3] = (const float*)d_in[1];  pp.B[3] = (const float*)d_in[17]; pp.dst[3] = Qb;  // Q (scaled)
    pp.src[4] = (const float*)d_in[3];  pp.B[4] = (const float*)d_in[19]; pp.dst[4] = Kb;  // K
    pp.src[5] = (const float*)d_in[3];  pp.B[5] = (const float*)d_in[21]; pp.dst[5] = Vb;  // V
    pp.src[6] = (const float*)d_in[3];  pp.B[6] = (const float*)d_in[13]; pp.dst[6] = Tt;  // t_tok
    pp.src[7] = (const float*)d_in[5];  pp.B[7] = (const float*)d_in[15]; pp.dst[7] = Vp;  // v_patch
    hipLaunchKernelGGL(proj_kernel, dim3(910), dim3(256), 0, stream, pp);

    hipLaunchKernelGGL(attn_kernel, dim3(4096), dim3(256), 0, stream,
                       (const bf16*)Qb, (const bf16*)Kb, (const bf16*)Vb, Ctx);
    hipLaunchKernelGGL(cll_kernel, dim3(512), dim3(256), 0, stream,
                       (const bf16*)Tt, (const bf16*)Vp,
                       (const float*)Ctx, (const float*)t, (const float*)d, (const float*)v,
                       (const float*)d_in[22], (const float*)d_in[23], (float*)d_out);
}